// Round 9
// baseline (95.238 us; speedup 1.0000x reference)
//
#include <hip/hip_runtime.h>
#include <hip/hip_cooperative_groups.h>
#include <math.h>

namespace cg = cooperative_groups;

#define NLEAVES 8192
constexpr int NT    = 512;          // threads/block (8 waves)
constexpr int NSLOT = 16;           // 32-lane q-slots

// ---- LDS layout (floats) ----
// E4[lr*32 + (lp ^ (lr&7))] = exp(trans[lp][l][4*r4..+3]), lr = l*8+r4
constexpr int ROWP  = 36;                       // 144B rows, 16B-aligned
constexpr int PARTP = 33;
constexpr int OFF_E    = 0;
constexpr int OFF_BUF  = 32768;                 // 128 KB of E
constexpr int OFF_P0   = OFF_BUF + 32 * ROWP;
constexpr int OFF_P1   = OFF_P0 + NSLOT * PARTP;
constexpr int OFF_P2   = OFF_P1 + NSLOT * PARTP;
constexpr int OFF_P3   = OFF_P2 + NSLOT * PARTP;
constexpr int OFF_R    = OFF_P3 + NSLOT * PARTP;
constexpr int SMEM_F32 = OFF_R + 64;
constexpr size_t SMEM_BYTES = (size_t)SMEM_F32 * 4;   // ~141 KB -> 1 block/CU

__device__ __forceinline__ void build_E(const float* __restrict__ trans,
                                        float* sm, int tid, int bid) {
    const float4* t4 = (const float4*)trans;    // t4[lp_s*256 + lr]
    float4* E4 = (float4*)(sm + OFF_E);
    #pragma unroll
    for (int it = 0; it < 16; ++it) {
        const int idx = (tid + it * NT + bid * 32) & 8191;  // block-rotated
        const int lp_s = idx >> 8, lr = idx & 255;
        float4 v = t4[idx];
        float4 e;
        e.x = expf(v.x); e.y = expf(v.y); e.z = expf(v.z); e.w = expf(v.w);
        E4[lr * 32 + (lp_s ^ (lr & 7))] = e;
    }
}

// Reduce IN consecutive score rows (rows blk*IN ..) through LEVELS levels in
// LDS; root row -> outp[blk*32+lp]. NTOT = global node count at input level.
// Levels with m>=4 nodes: quad-sharing (4 nodes per E read). m<=2: pair path.
template<int IN, int LEVELS>
__device__ __forceinline__
void subtree(const float* __restrict__ in, float* __restrict__ outp,
             const float* __restrict__ iem, int NTOT, int blk,
             float* sm, int tid, int lp, int q) {
    float* Ef  = sm + OFF_E;
    float* buf = sm + OFF_BUF;
    float* p0  = sm + OFF_P0;
    float* p1  = sm + OFF_P1;
    float* p2  = sm + OFF_P2;
    float* p3  = sm + OFF_P3;
    float* rm  = sm + OFF_R;

    // prepass: rows -> exp(v - rowmax); rowmax -> rm (parity 0)
    for (int rr = q; rr < IN; rr += NSLOT) {
        float v = in[(blk * IN + rr) * 32 + lp];
        float gm = v;
        #pragma unroll
        for (int kk = 16; kk >= 1; kk >>= 1) gm = fmaxf(gm, __shfl_xor(gm, kk));
        buf[rr * ROWP + lp] = expf(v - gm);
        if (lp == 0) rm[rr] = gm;
    }
    __syncthreads();

    #pragma unroll
    for (int k = 1; k <= LEVELS; ++k) {
        const int m = IN >> k;                    // nodes this level
        const float* rprev = rm + ((k & 1) ? 0 : 32);
        float*       rnext = rm + ((k & 1) ? 32 : 0);
        int S_acc;                                // segments to sum in phase 2

        if (m >= 4) {
            // ---- quad phase 1: 4 nodes share each E read ----
            const int nq   = m >> 2;
            const int S    = NSLOT / nq;
            const int llen = 32 / S;
            const int lgnq = (nq == 4) ? 2 : (nq == 2) ? 1 : 0;
            const int quad = q & (nq - 1);
            const int seg  = q >> lgnq;
            const int base = 8 * quad;
            S_acc = S;

            float4 b0[8], b1[8], b2[8], b3[8];
            {
                const float4* pb0 = (const float4*)(buf + (base + 1) * ROWP);
                const float4* pb1 = (const float4*)(buf + (base + 3) * ROWP);
                const float4* pb2 = (const float4*)(buf + (base + 5) * ROWP);
                const float4* pb3 = (const float4*)(buf + (base + 7) * ROWP);
                #pragma unroll
                for (int r = 0; r < 8; ++r) {
                    b0[r] = pb0[r]; b1[r] = pb1[r];
                    b2[r] = pb2[r]; b3[r] = pb3[r];
                }
            }
            float s0 = 0.f, s1v = 0.f, s2v = 0.f, s3v = 0.f;
            #pragma unroll
            for (int li = 0; li < llen; ++li) {
                const int l = seg * llen + li;
                const float a0 = buf[(base + 0) * ROWP + l];
                const float a1 = buf[(base + 2) * ROWP + l];
                const float a2 = buf[(base + 4) * ROWP + l];
                const float a3 = buf[(base + 6) * ROWP + l];
                const float4* E4p = (const float4*)Ef + l * 256;
                float u0 = 0.f, u1 = 0.f, u2 = 0.f, u3 = 0.f;
                #pragma unroll
                for (int r4 = 0; r4 < 8; ++r4) {
                    const float4 e = E4p[r4 * 32 + (lp ^ r4)];
                    u0 = fmaf(b0[r4].x, e.x, u0); u0 = fmaf(b0[r4].y, e.y, u0);
                    u0 = fmaf(b0[r4].z, e.z, u0); u0 = fmaf(b0[r4].w, e.w, u0);
                    u1 = fmaf(b1[r4].x, e.x, u1); u1 = fmaf(b1[r4].y, e.y, u1);
                    u1 = fmaf(b1[r4].z, e.z, u1); u1 = fmaf(b1[r4].w, e.w, u1);
                    u2 = fmaf(b2[r4].x, e.x, u2); u2 = fmaf(b2[r4].y, e.y, u2);
                    u2 = fmaf(b2[r4].z, e.z, u2); u2 = fmaf(b2[r4].w, e.w, u2);
                    u3 = fmaf(b3[r4].x, e.x, u3); u3 = fmaf(b3[r4].y, e.y, u3);
                    u3 = fmaf(b3[r4].w, e.w, u3); u3 = fmaf(b3[r4].z, e.z, u3);
                }
                s0  = fmaf(a0, u0, s0);
                s1v = fmaf(a1, u1, s1v);
                s2v = fmaf(a2, u2, s2v);
                s3v = fmaf(a3, u3, s3v);
            }
            p0[q * PARTP + lp] = s0;
            p1[q * PARTP + lp] = s1v;
            p2[q * PARTP + lp] = s2v;
            p3[q * PARTP + lp] = s3v;
        } else {
            // ---- pair phase 1 (m <= 2) ----
            const int llen = 2;                   // S = 16
            const int seg  = q;
            S_acc = 16;
            float4 b0[8], b1[8];
            {
                const float4* pb0 = (const float4*)(buf + 1 * ROWP);
                const float4* pb1 = (const float4*)(buf + 3 * ROWP);
                #pragma unroll
                for (int r = 0; r < 8; ++r) { b0[r] = pb0[r]; b1[r] = pb1[r]; }
            }
            float s0 = 0.f, s1v = 0.f;
            #pragma unroll
            for (int li = 0; li < llen; ++li) {
                const int l = seg * llen + li;
                const float a0 = buf[0 * ROWP + l];
                const float a1 = buf[2 * ROWP + l];
                const float4* E4p = (const float4*)Ef + l * 256;
                float u0 = 0.f, u1 = 0.f;
                #pragma unroll
                for (int r4 = 0; r4 < 8; ++r4) {
                    const float4 e = E4p[r4 * 32 + (lp ^ r4)];
                    u0 = fmaf(b0[r4].x, e.x, u0); u0 = fmaf(b0[r4].y, e.y, u0);
                    u0 = fmaf(b0[r4].z, e.z, u0); u0 = fmaf(b0[r4].w, e.w, u0);
                    u1 = fmaf(b1[r4].x, e.x, u1); u1 = fmaf(b1[r4].y, e.y, u1);
                    u1 = fmaf(b1[r4].z, e.z, u1); u1 = fmaf(b1[r4].w, e.w, u1);
                }
                s0  = fmaf(a0, u0, s0);
                s1v = fmaf(a1, u1, s1v);
            }
            p0[q * PARTP + lp] = s0;
            p1[q * PARTP + lp] = s1v;
        }
        __syncthreads();

        // ---- phase 2: combine partials, add emissions, log ----
        if (tid < m * 32) {
            const int node = q;
            float acc = 0.f;
            if (m >= 4) {
                const int nq = m >> 2;
                const int j  = node & 3;
                const int qd = node >> 2;
                const float* pp = (j == 0) ? p0 : (j == 1) ? p1 : (j == 2) ? p2 : p3;
                #pragma unroll
                for (int s = 0; s < 16; ++s) {
                    if (s < S_acc) acc += pp[(s * nq + qd) * PARTP + lp];
                }
            } else {
                const float* pp = (node & 1) ? p1 : p0;
                #pragma unroll
                for (int s = 0; s < 16; ++s) acc += pp[s * PARTP + lp];
            }
            const float em = iem[(NLEAVES - 2 * (NTOT >> k) + blk * m + node) * 32 + lp];
            const float raw = em + rprev[2 * node] + rprev[2 * node + 1] + logf(acc);
            if (k == LEVELS) {
                outp[blk * 32 + lp] = raw;        // m==1, node==0
            } else {
                float gm = raw;
                #pragma unroll
                for (int kk = 16; kk >= 1; kk >>= 1) gm = fmaxf(gm, __shfl_xor(gm, kk));
                buf[node * ROWP + lp] = expf(raw - gm);   // in-place: phase2 reads only p/rm
                if (lp == 0) rnext[node] = gm;
            }
        }
        __syncthreads();
    }
}

// Single COOPERATIVE dispatch, 256 blocks (1/CU, co-resident by construction).
// The cross-XCD handoffs use the vendor grid barrier (cg::this_grid().sync()),
// whose memory semantics are the runtime's responsibility -- R6/R7 proved
// hand-rolled fence+atomic handoff is racy on gfx950, so we don't hand-roll.
// Stage2 (8 blocks) and stage3 (1 block) reuse the exp(T) already in LDS --
// no rebuild, unlike the 2-kernel version. All blocks reach both syncs.
__global__ __launch_bounds__(NT, 1)
void coop_tree(const float* __restrict__ leaf, const float* __restrict__ iem,
               const float* __restrict__ trans, float* __restrict__ s1,
               float* __restrict__ s2, float* __restrict__ out) {
    extern __shared__ __align__(16) float sm[];
    const int tid = threadIdx.x, lp = tid & 31, q = tid >> 5;
    const int bid = blockIdx.x;

    build_E(trans, sm, tid, bid);
    subtree<32, 5>(leaf, s1, iem, 8192, bid, sm, tid, lp, q);

    cg::this_grid().sync();

    if (bid < 8)
        subtree<32, 5>(s1, s2, iem, 256, bid, sm, tid, lp, q);

    cg::this_grid().sync();

    if (bid == 0)
        subtree<8, 3>(s2, out, iem, 8, 0, sm, tid, lp, q);
}

extern "C" void kernel_launch(void* const* d_in, const int* in_sizes, int n_in,
                              void* d_out, int out_size, void* d_ws, size_t ws_size,
                              hipStream_t stream) {
    const float* leaf  = (const float*)d_in[0];   // [8192,32]
    const float* iem   = (const float*)d_in[1];   // [8191,32]
    const float* trans = (const float*)d_in[2];   // [32,32,32]
    float* out = (float*)d_out;                   // [32]

    float* s1 = (float*)d_ws;                     // 256*32 f32
    float* s2 = s1 + 256 * 32;                    // 8*32 f32

    (void)hipFuncSetAttribute((const void*)coop_tree,
                              hipFuncAttributeMaxDynamicSharedMemorySize,
                              (int)SMEM_BYTES);

    void* args[] = { (void*)&leaf, (void*)&iem, (void*)&trans,
                     (void*)&s1, (void*)&s2, (void*)&out };
    (void)hipLaunchCooperativeKernel((const void*)coop_tree,
                                     dim3(256), dim3(NT),
                                     args, (unsigned)SMEM_BYTES, stream);
}

// Round 10
// 38.061 us; speedup vs baseline: 2.5022x; 2.5022x over previous
//
#include <hip/hip_runtime.h>
#include <math.h>

#define NLEAVES 8192
constexpr int NT    = 512;          // threads/block (8 waves)
constexpr int NSLOT = 16;           // 32-lane q-slots

// ---- LDS layout (floats) ----
// E4[lr*32 + (lp ^ (lr&7))] = exp(trans[lp][l][4*r4..+3]), lr = l*8+r4
constexpr int ROWP  = 36;                       // 144B rows, 16B-aligned
constexpr int PARTP = 33;
constexpr int OFF_E    = 0;
constexpr int OFF_BUF  = 32768;                 // 128 KB of E
constexpr int OFF_P0   = OFF_BUF + 32 * ROWP;
constexpr int OFF_P1   = OFF_P0 + NSLOT * PARTP;
constexpr int OFF_P2   = OFF_P1 + NSLOT * PARTP;
constexpr int OFF_P3   = OFF_P2 + NSLOT * PARTP;
constexpr int OFF_R    = OFF_P3 + NSLOT * PARTP;
constexpr int OFF_FLAG = OFF_R + 64;
constexpr int SMEM_F32 = OFF_FLAG + 4;
constexpr size_t SMEM_BYTES = (size_t)SMEM_F32 * 4;   // ~141 KB -> 1 block/CU

// Build exp(T) into LDS from raw trans (native v_exp_f32: __expf).
__device__ __forceinline__ void build_E(const float* __restrict__ trans,
                                        float* sm, int tid, int bid) {
    const float4* t4 = (const float4*)trans;    // t4[lp_s*256 + lr]
    float4* E4 = (float4*)(sm + OFF_E);
    #pragma unroll
    for (int it = 0; it < 16; ++it) {
        const int idx = (tid + it * NT + bid * 32) & 8191;  // block-rotated
        const int lp_s = idx >> 8, lr = idx & 255;
        float4 v = t4[idx];
        float4 e;
        e.x = __expf(v.x); e.y = __expf(v.y); e.z = __expf(v.z); e.w = __expf(v.w);
        E4[lr * 32 + (lp_s ^ (lr & 7))] = e;
    }
}

// Load pre-exponentiated, pre-swizzled E table straight from ws (written by
// k1's block 0). Pure coalesced 128 KB copy, L2/L3-hot, no expf/swizzle math.
__device__ __forceinline__ void load_E(const float* __restrict__ wsE,
                                       float* sm, int tid) {
    const float4* src = (const float4*)wsE;
    float4* E4 = (float4*)(sm + OFF_E);
    #pragma unroll
    for (int it = 0; it < 16; ++it)
        E4[tid + it * NT] = src[tid + it * NT];
}

// Reduce IN consecutive score rows (rows blk*IN ..) through LEVELS levels in
// LDS; root row -> outp[blk*32+lp]. NTOT = global node count at input level.
// Levels with m>=4 nodes: quad-sharing (4 nodes per E read). m<=2: pair path.
template<int IN, int LEVELS>
__device__ __forceinline__
void subtree(const float* __restrict__ in, float* __restrict__ outp,
             const float* __restrict__ iem, int NTOT, int blk,
             float* sm, int tid, int lp, int q) {
    float* Ef  = sm + OFF_E;
    float* buf = sm + OFF_BUF;
    float* p0  = sm + OFF_P0;
    float* p1  = sm + OFF_P1;
    float* p2  = sm + OFF_P2;
    float* p3  = sm + OFF_P3;
    float* rm  = sm + OFF_R;

    // prepass: rows -> exp(v - rowmax); rowmax -> rm (parity 0)
    for (int rr = q; rr < IN; rr += NSLOT) {
        float v = in[(blk * IN + rr) * 32 + lp];
        float gm = v;
        #pragma unroll
        for (int kk = 16; kk >= 1; kk >>= 1) gm = fmaxf(gm, __shfl_xor(gm, kk));
        buf[rr * ROWP + lp] = __expf(v - gm);
        if (lp == 0) rm[rr] = gm;
    }
    __syncthreads();

    #pragma unroll
    for (int k = 1; k <= LEVELS; ++k) {
        const int m = IN >> k;                    // nodes this level
        const float* rprev = rm + ((k & 1) ? 0 : 32);
        float*       rnext = rm + ((k & 1) ? 32 : 0);
        int S_acc;                                // segments to sum in phase 2

        if (m >= 4) {
            // ---- quad phase 1: 4 nodes share each E read ----
            const int nq   = m >> 2;
            const int S    = NSLOT / nq;
            const int llen = 32 / S;
            const int lgnq = (nq == 4) ? 2 : (nq == 2) ? 1 : 0;
            const int quad = q & (nq - 1);
            const int seg  = q >> lgnq;
            const int base = 8 * quad;
            S_acc = S;

            float4 b0[8], b1[8], b2[8], b3[8];
            {
                const float4* pb0 = (const float4*)(buf + (base + 1) * ROWP);
                const float4* pb1 = (const float4*)(buf + (base + 3) * ROWP);
                const float4* pb2 = (const float4*)(buf + (base + 5) * ROWP);
                const float4* pb3 = (const float4*)(buf + (base + 7) * ROWP);
                #pragma unroll
                for (int r = 0; r < 8; ++r) {
                    b0[r] = pb0[r]; b1[r] = pb1[r];
                    b2[r] = pb2[r]; b3[r] = pb3[r];
                }
            }
            float s0 = 0.f, s1v = 0.f, s2v = 0.f, s3v = 0.f;
            #pragma unroll
            for (int li = 0; li < llen; ++li) {
                const int l = seg * llen + li;
                const float a0 = buf[(base + 0) * ROWP + l];
                const float a1 = buf[(base + 2) * ROWP + l];
                const float a2 = buf[(base + 4) * ROWP + l];
                const float a3 = buf[(base + 6) * ROWP + l];
                const float4* E4p = (const float4*)Ef + l * 256;
                float u0 = 0.f, u1 = 0.f, u2 = 0.f, u3 = 0.f;
                #pragma unroll
                for (int r4 = 0; r4 < 8; ++r4) {
                    const float4 e = E4p[r4 * 32 + (lp ^ r4)];
                    u0 = fmaf(b0[r4].x, e.x, u0); u0 = fmaf(b0[r4].y, e.y, u0);
                    u0 = fmaf(b0[r4].z, e.z, u0); u0 = fmaf(b0[r4].w, e.w, u0);
                    u1 = fmaf(b1[r4].x, e.x, u1); u1 = fmaf(b1[r4].y, e.y, u1);
                    u1 = fmaf(b1[r4].z, e.z, u1); u1 = fmaf(b1[r4].w, e.w, u1);
                    u2 = fmaf(b2[r4].x, e.x, u2); u2 = fmaf(b2[r4].y, e.y, u2);
                    u2 = fmaf(b2[r4].z, e.z, u2); u2 = fmaf(b2[r4].w, e.w, u2);
                    u3 = fmaf(b3[r4].x, e.x, u3); u3 = fmaf(b3[r4].y, e.y, u3);
                    u3 = fmaf(b3[r4].w, e.w, u3); u3 = fmaf(b3[r4].z, e.z, u3);
                }
                s0  = fmaf(a0, u0, s0);
                s1v = fmaf(a1, u1, s1v);
                s2v = fmaf(a2, u2, s2v);
                s3v = fmaf(a3, u3, s3v);
            }
            p0[q * PARTP + lp] = s0;
            p1[q * PARTP + lp] = s1v;
            p2[q * PARTP + lp] = s2v;
            p3[q * PARTP + lp] = s3v;
        } else {
            // ---- pair phase 1 (m <= 2) ----
            const int llen = 2;                   // S = 16
            const int seg  = q;
            S_acc = 16;
            float4 b0[8], b1[8];
            {
                const float4* pb0 = (const float4*)(buf + 1 * ROWP);
                const float4* pb1 = (const float4*)(buf + 3 * ROWP);
                #pragma unroll
                for (int r = 0; r < 8; ++r) { b0[r] = pb0[r]; b1[r] = pb1[r]; }
            }
            float s0 = 0.f, s1v = 0.f;
            #pragma unroll
            for (int li = 0; li < llen; ++li) {
                const int l = seg * llen + li;
                const float a0 = buf[0 * ROWP + l];
                const float a1 = buf[2 * ROWP + l];
                const float4* E4p = (const float4*)Ef + l * 256;
                float u0 = 0.f, u1 = 0.f;
                #pragma unroll
                for (int r4 = 0; r4 < 8; ++r4) {
                    const float4 e = E4p[r4 * 32 + (lp ^ r4)];
                    u0 = fmaf(b0[r4].x, e.x, u0); u0 = fmaf(b0[r4].y, e.y, u0);
                    u0 = fmaf(b0[r4].z, e.z, u0); u0 = fmaf(b0[r4].w, e.w, u0);
                    u1 = fmaf(b1[r4].x, e.x, u1); u1 = fmaf(b1[r4].y, e.y, u1);
                    u1 = fmaf(b1[r4].z, e.z, u1); u1 = fmaf(b1[r4].w, e.w, u1);
                }
                s0  = fmaf(a0, u0, s0);
                s1v = fmaf(a1, u1, s1v);
            }
            p0[q * PARTP + lp] = s0;
            p1[q * PARTP + lp] = s1v;
        }
        __syncthreads();

        // ---- phase 2: combine partials, add emissions, log ----
        if (tid < m * 32) {
            const int node = q;
            float acc = 0.f;
            if (m >= 4) {
                const int nq = m >> 2;
                const int j  = node & 3;
                const int qd = node >> 2;
                const float* pp = (j == 0) ? p0 : (j == 1) ? p1 : (j == 2) ? p2 : p3;
                #pragma unroll
                for (int s = 0; s < 16; ++s) {
                    if (s < S_acc) acc += pp[(s * nq + qd) * PARTP + lp];
                }
            } else {
                const float* pp = (node & 1) ? p1 : p0;
                #pragma unroll
                for (int s = 0; s < 16; ++s) acc += pp[s * PARTP + lp];
            }
            const float em = iem[(NLEAVES - 2 * (NTOT >> k) + blk * m + node) * 32 + lp];
            const float raw = em + rprev[2 * node] + rprev[2 * node + 1] + __logf(acc);
            if (k == LEVELS) {
                outp[blk * 32 + lp] = raw;        // m==1, node==0
            } else {
                float gm = raw;
                #pragma unroll
                for (int kk = 16; kk >= 1; kk >>= 1) gm = fmaxf(gm, __shfl_xor(gm, kk));
                buf[node * ROWP + lp] = __expf(raw - gm);  // in-place: phase2 reads only p/rm
                if (lp == 0) rnext[node] = gm;
            }
        }
        __syncthreads();
    }
}

// K1: 256 blocks, 32 leaves each -> s1[256 rows]. Block 0 additionally spills
// its finished swizzled exp(T) table to wsE so the tail can skip the 32K-expf
// rebuild. The k1->tail kernel boundary is the system-level flush for both s1
// and wsE (R6/R7 proved intra-kernel 256-block handoff is racy; R9 proved
// grid.sync costs ~37us each -- kernel boundary is the cheapest safe flush).
__global__ __launch_bounds__(NT, 1)
void k1_kernel(const float* __restrict__ leaf, float* __restrict__ s1,
               const float* __restrict__ iem, const float* __restrict__ trans,
               float* __restrict__ wsE) {
    extern __shared__ __align__(16) float sm[];
    const int tid = threadIdx.x, lp = tid & 31, q = tid >> 5;
    build_E(trans, sm, tid, blockIdx.x);
    if (blockIdx.x == 0) {
        __syncthreads();                          // E fully built before readback
        const float4* E4 = (const float4*)(sm + OFF_E);
        float4* dst = (float4*)wsE;
        #pragma unroll
        for (int it = 0; it < 16; ++it)
            dst[tid + it * NT] = E4[tid + it * NT];
    }
    subtree<32, 5>(leaf, s1, iem, 8192, blockIdx.x, sm, tid, lp, q);
}

// Tail: 8 blocks reduce s1(256 rows) -> s2(8 rows); last arriver does 8->out.
// E comes pre-exp'd from wsE (straight copy). Persistent counter, never
// reset: among any 8 consecutive fetch_add returns exactly one satisfies
// (old&7)==7 (wrap-safe, works from the 0xAA poison) -> no memset node.
// Fence pattern is R5/R8's verbatim.
__global__ __launch_bounds__(NT, 1)
void tail_kernel(const float* __restrict__ s1, float* __restrict__ s2,
                 float* __restrict__ out, const float* __restrict__ iem,
                 const float* __restrict__ wsE, unsigned* __restrict__ cnt) {
    extern __shared__ __align__(16) float sm[];
    const int tid = threadIdx.x, lp = tid & 31, q = tid >> 5;
    int* flag = (int*)(sm + OFF_FLAG);
    load_E(wsE, sm, tid);
    subtree<32, 5>(s1, s2, iem, 256, blockIdx.x, sm, tid, lp, q);

    if (tid == 0) {
        __threadfence();                              // release s2 row device-wide
        unsigned old = atomicAdd(cnt, 1u);
        *flag = ((old & 7u) == 7u) ? 1 : 0;
    }
    __syncthreads();
    if (!*flag) return;
    if (tid == 0) __threadfence();                    // acquire
    __syncthreads();

    subtree<8, 3>(s2, out, iem, 8, 0, sm, tid, lp, q);
}

extern "C" void kernel_launch(void* const* d_in, const int* in_sizes, int n_in,
                              void* d_out, int out_size, void* d_ws, size_t ws_size,
                              hipStream_t stream) {
    const float* leaf  = (const float*)d_in[0];   // [8192,32]
    const float* iem   = (const float*)d_in[1];   // [8191,32]
    const float* trans = (const float*)d_in[2];   // [32,32,32]
    float* out = (float*)d_out;                   // [32]

    float* s1     = (float*)d_ws;                 // 256*32 f32
    float* s2     = s1 + 256 * 32;                // 8*32 f32
    unsigned* cnt = (unsigned*)(s2 + 8 * 32);     // 1 u32, never reset (mod trick)
    float* wsE    = (float*)d_ws + 8704;          // 32768 f32, 16B-aligned

    (void)hipFuncSetAttribute((const void*)k1_kernel,
                              hipFuncAttributeMaxDynamicSharedMemorySize,
                              (int)SMEM_BYTES);
    (void)hipFuncSetAttribute((const void*)tail_kernel,
                              hipFuncAttributeMaxDynamicSharedMemorySize,
                              (int)SMEM_BYTES);

    k1_kernel<<<256, NT, SMEM_BYTES, stream>>>(leaf, s1, iem, trans, wsE);
    tail_kernel<<<8, NT, SMEM_BYTES, stream>>>(s1, s2, out, iem, wsE, cnt);
}

// Round 11
// 35.850 us; speedup vs baseline: 2.6566x; 1.0617x over previous
//
#include <hip/hip_runtime.h>
#include <math.h>

#define NLEAVES 8192
constexpr int NT    = 512;          // threads/block (8 waves)
constexpr int NSLOT = 16;           // 32-lane q-slots

typedef float f32x2 __attribute__((ext_vector_type(2)));

#if __has_builtin(__builtin_elementwise_fma)
#define PKFMA(B, E, U) (U) = __builtin_elementwise_fma((B), (E), (U))
#else
#define PKFMA(B, E, U) do { (U).x = fmaf((B).x, (E).x, (U).x); \
                            (U).y = fmaf((B).y, (E).y, (U).y); } while (0)
#endif

// ---- LDS layout (floats) ----
// E4[lr*32 + (lp ^ (lr&7))] = exp(trans[lp][l][4*r4..+3]), lr = l*8+r4
constexpr int ROWP  = 36;                       // 144B rows, 16B-aligned
constexpr int PARTP = 33;
constexpr int OFF_E    = 0;
constexpr int OFF_BUF  = 32768;                 // 128 KB of E
constexpr int OFF_P0   = OFF_BUF + 32 * ROWP;
constexpr int OFF_P1   = OFF_P0 + NSLOT * PARTP;
constexpr int OFF_P2   = OFF_P1 + NSLOT * PARTP;
constexpr int OFF_P3   = OFF_P2 + NSLOT * PARTP;
constexpr int OFF_R    = OFF_P3 + NSLOT * PARTP;
constexpr int OFF_FLAG = OFF_R + 64;
constexpr int SMEM_F32 = OFF_FLAG + 4;
constexpr size_t SMEM_BYTES = (size_t)SMEM_F32 * 4;   // ~141 KB -> 1 block/CU

// Build exp(T) into LDS from raw trans (native v_exp_f32).
__device__ __forceinline__ void build_E(const float* __restrict__ trans,
                                        float* sm, int tid, int bid) {
    const float4* t4 = (const float4*)trans;    // t4[lp_s*256 + lr]
    float4* E4 = (float4*)(sm + OFF_E);
    #pragma unroll
    for (int it = 0; it < 16; ++it) {
        const int idx = (tid + it * NT + bid * 32) & 8191;  // block-rotated
        const int lp_s = idx >> 8, lr = idx & 255;
        float4 v = t4[idx];
        float4 e;
        e.x = __expf(v.x); e.y = __expf(v.y); e.z = __expf(v.z); e.w = __expf(v.w);
        E4[lr * 32 + (lp_s ^ (lr & 7))] = e;
    }
}

// Load pre-exponentiated, pre-swizzled E straight from ws (written by k1
// block 0): pure coalesced 128 KB copy, L2/L3-hot, no expf/swizzle math.
__device__ __forceinline__ void load_E(const float* __restrict__ wsE,
                                       float* sm, int tid) {
    const float4* src = (const float4*)wsE;
    float4* E4 = (float4*)(sm + OFF_E);
    #pragma unroll
    for (int it = 0; it < 16; ++it)
        E4[tid + it * NT] = src[tid + it * NT];
}

// Reduce IN consecutive score rows (rows blk*IN ..) through LEVELS levels in
// LDS; root row -> outp[blk*32+lp]. NTOT = global node count at input level.
// Levels with m>=4: quad-sharing (4 nodes per E read). m<=2: pair path.
// Inner loops use f32x2 packed FMA (v_pk_fma_f32: 2 MACs/inst).
template<int IN, int LEVELS>
__device__ __forceinline__
void subtree(const float* __restrict__ in, float* __restrict__ outp,
             const float* __restrict__ iem, int NTOT, int blk,
             float* sm, int tid, int lp, int q) {
    float* Ef  = sm + OFF_E;
    float* buf = sm + OFF_BUF;
    float* p0  = sm + OFF_P0;
    float* p1  = sm + OFF_P1;
    float* p2  = sm + OFF_P2;
    float* p3  = sm + OFF_P3;
    float* rm  = sm + OFF_R;

    // prepass: rows -> exp(v - rowmax); rowmax -> rm (parity 0)
    for (int rr = q; rr < IN; rr += NSLOT) {
        float v = in[(blk * IN + rr) * 32 + lp];
        float gm = v;
        #pragma unroll
        for (int kk = 16; kk >= 1; kk >>= 1) gm = fmaxf(gm, __shfl_xor(gm, kk));
        buf[rr * ROWP + lp] = __expf(v - gm);
        if (lp == 0) rm[rr] = gm;
    }
    __syncthreads();

    #pragma unroll
    for (int k = 1; k <= LEVELS; ++k) {
        const int m = IN >> k;                    // nodes this level
        const float* rprev = rm + ((k & 1) ? 0 : 32);
        float*       rnext = rm + ((k & 1) ? 32 : 0);
        int S_acc;                                // segments to sum in phase 2

        if (m >= 4) {
            // ---- quad phase 1: 4 nodes share each E read ----
            const int nq   = m >> 2;
            const int S    = NSLOT / nq;
            const int llen = 32 / S;
            const int lgnq = (nq == 4) ? 2 : (nq == 2) ? 1 : 0;
            const int quad = q & (nq - 1);
            const int seg  = q >> lgnq;
            const int base = 8 * quad;
            S_acc = S;

            float4 b0[8], b1[8], b2[8], b3[8];
            {
                const float4* pb0 = (const float4*)(buf + (base + 1) * ROWP);
                const float4* pb1 = (const float4*)(buf + (base + 3) * ROWP);
                const float4* pb2 = (const float4*)(buf + (base + 5) * ROWP);
                const float4* pb3 = (const float4*)(buf + (base + 7) * ROWP);
                #pragma unroll
                for (int r = 0; r < 8; ++r) {
                    b0[r] = pb0[r]; b1[r] = pb1[r];
                    b2[r] = pb2[r]; b3[r] = pb3[r];
                }
            }
            float s0 = 0.f, s1v = 0.f, s2v = 0.f, s3v = 0.f;
            #pragma unroll
            for (int li = 0; li < llen; ++li) {
                const int l = seg * llen + li;
                const float a0 = buf[(base + 0) * ROWP + l];
                const float a1 = buf[(base + 2) * ROWP + l];
                const float a2 = buf[(base + 4) * ROWP + l];
                const float a3 = buf[(base + 6) * ROWP + l];
                const float4* E4p = (const float4*)Ef + l * 256;
                f32x2 u0 = {0.f, 0.f}, u1 = {0.f, 0.f};
                f32x2 u2 = {0.f, 0.f}, u3 = {0.f, 0.f};
                #pragma unroll
                for (int r4 = 0; r4 < 8; ++r4) {
                    const float4 e = E4p[r4 * 32 + (lp ^ r4)];
                    const f32x2 e01 = {e.x, e.y}, e23 = {e.z, e.w};
                    PKFMA(((f32x2){b0[r4].x, b0[r4].y}), e01, u0);
                    PKFMA(((f32x2){b0[r4].z, b0[r4].w}), e23, u0);
                    PKFMA(((f32x2){b1[r4].x, b1[r4].y}), e01, u1);
                    PKFMA(((f32x2){b1[r4].z, b1[r4].w}), e23, u1);
                    PKFMA(((f32x2){b2[r4].x, b2[r4].y}), e01, u2);
                    PKFMA(((f32x2){b2[r4].z, b2[r4].w}), e23, u2);
                    PKFMA(((f32x2){b3[r4].x, b3[r4].y}), e01, u3);
                    PKFMA(((f32x2){b3[r4].z, b3[r4].w}), e23, u3);
                }
                s0  = fmaf(a0, u0.x + u0.y, s0);
                s1v = fmaf(a1, u1.x + u1.y, s1v);
                s2v = fmaf(a2, u2.x + u2.y, s2v);
                s3v = fmaf(a3, u3.x + u3.y, s3v);
            }
            p0[q * PARTP + lp] = s0;
            p1[q * PARTP + lp] = s1v;
            p2[q * PARTP + lp] = s2v;
            p3[q * PARTP + lp] = s3v;
        } else {
            // ---- pair phase 1 (m <= 2) ----
            const int llen = 2;                   // S = 16
            const int seg  = q;
            S_acc = 16;
            float4 b0[8], b1[8];
            {
                const float4* pb0 = (const float4*)(buf + 1 * ROWP);
                const float4* pb1 = (const float4*)(buf + 3 * ROWP);
                #pragma unroll
                for (int r = 0; r < 8; ++r) { b0[r] = pb0[r]; b1[r] = pb1[r]; }
            }
            float s0 = 0.f, s1v = 0.f;
            #pragma unroll
            for (int li = 0; li < llen; ++li) {
                const int l = seg * llen + li;
                const float a0 = buf[0 * ROWP + l];
                const float a1 = buf[2 * ROWP + l];
                const float4* E4p = (const float4*)Ef + l * 256;
                f32x2 u0 = {0.f, 0.f}, u1 = {0.f, 0.f};
                #pragma unroll
                for (int r4 = 0; r4 < 8; ++r4) {
                    const float4 e = E4p[r4 * 32 + (lp ^ r4)];
                    const f32x2 e01 = {e.x, e.y}, e23 = {e.z, e.w};
                    PKFMA(((f32x2){b0[r4].x, b0[r4].y}), e01, u0);
                    PKFMA(((f32x2){b0[r4].z, b0[r4].w}), e23, u0);
                    PKFMA(((f32x2){b1[r4].x, b1[r4].y}), e01, u1);
                    PKFMA(((f32x2){b1[r4].z, b1[r4].w}), e23, u1);
                }
                s0  = fmaf(a0, u0.x + u0.y, s0);
                s1v = fmaf(a1, u1.x + u1.y, s1v);
            }
            p0[q * PARTP + lp] = s0;
            p1[q * PARTP + lp] = s1v;
        }
        __syncthreads();

        // ---- phase 2: combine partials, add emissions, log ----
        if (tid < m * 32) {
            const int node = q;
            float acc = 0.f;
            if (m >= 4) {
                const int nq = m >> 2;
                const int j  = node & 3;
                const int qd = node >> 2;
                const float* pp = (j == 0) ? p0 : (j == 1) ? p1 : (j == 2) ? p2 : p3;
                #pragma unroll
                for (int s = 0; s < 16; ++s) {
                    if (s < S_acc) acc += pp[(s * nq + qd) * PARTP + lp];
                }
            } else {
                const float* pp = (node & 1) ? p1 : p0;
                #pragma unroll
                for (int s = 0; s < 16; ++s) acc += pp[s * PARTP + lp];
            }
            const float em = iem[(NLEAVES - 2 * (NTOT >> k) + blk * m + node) * 32 + lp];
            const float raw = em + rprev[2 * node] + rprev[2 * node + 1] + __logf(acc);
            if (k == LEVELS) {
                outp[blk * 32 + lp] = raw;        // m==1, node==0
            } else {
                float gm = raw;
                #pragma unroll
                for (int kk = 16; kk >= 1; kk >>= 1) gm = fmaxf(gm, __shfl_xor(gm, kk));
                buf[node * ROWP + lp] = __expf(raw - gm);  // in-place: phase2 reads only p/rm
                if (lp == 0) rnext[node] = gm;
            }
        }
        __syncthreads();
    }
}

// K1: 256 blocks, 32 leaves each -> s1[256 rows]. Block 0 spills its finished
// swizzled exp(T) to wsE so the tail skips the expf rebuild. Kernel boundary
// = the system-level flush for s1/wsE (R6/R7: intra-kernel 256-block handoff
// is racy; R9: grid.sync costs ~37us each).
__global__ __launch_bounds__(NT, 1)
void k1_kernel(const float* __restrict__ leaf, float* __restrict__ s1,
               const float* __restrict__ iem, const float* __restrict__ trans,
               float* __restrict__ wsE) {
    extern __shared__ __align__(16) float sm[];
    const int tid = threadIdx.x, lp = tid & 31, q = tid >> 5;
    build_E(trans, sm, tid, blockIdx.x);
    if (blockIdx.x == 0) {
        __syncthreads();                          // E fully built before readback
        const float4* E4 = (const float4*)(sm + OFF_E);
        float4* dst = (float4*)wsE;
        #pragma unroll
        for (int it = 0; it < 16; ++it)
            dst[tid + it * NT] = E4[tid + it * NT];
    }
    subtree<32, 5>(leaf, s1, iem, 8192, blockIdx.x, sm, tid, lp, q);
}

// Tail: 16 blocks reduce s1(256 rows) -> s2(16 rows) via 4 levels each; the
// last arriver reduces s2(16) -> out via 4 more levels. Rebalanced from 8x5+3
// to 16x4+4: doubles stage-2 parallelism and equalizes the two stages.
// Persistent counter, never reset: among any 16 consecutive fetch_add returns
// exactly one satisfies (old&15)==15 (wrap-safe from the 0xAA poison) -> no
// memset node. Fence pattern is R5/R8's verbatim.
__global__ __launch_bounds__(NT, 1)
void tail_kernel(const float* __restrict__ s1, float* __restrict__ s2,
                 float* __restrict__ out, const float* __restrict__ iem,
                 const float* __restrict__ wsE, unsigned* __restrict__ cnt) {
    extern __shared__ __align__(16) float sm[];
    const int tid = threadIdx.x, lp = tid & 31, q = tid >> 5;
    int* flag = (int*)(sm + OFF_FLAG);
    load_E(wsE, sm, tid);
    subtree<16, 4>(s1, s2, iem, 256, blockIdx.x, sm, tid, lp, q);

    if (tid == 0) {
        __threadfence();                              // release s2 row device-wide
        unsigned old = atomicAdd(cnt, 1u);
        *flag = ((old & 15u) == 15u) ? 1 : 0;
    }
    __syncthreads();
    if (!*flag) return;
    if (tid == 0) __threadfence();                    // acquire
    __syncthreads();

    subtree<16, 4>(s2, out, iem, 16, 0, sm, tid, lp, q);
}

extern "C" void kernel_launch(void* const* d_in, const int* in_sizes, int n_in,
                              void* d_out, int out_size, void* d_ws, size_t ws_size,
                              hipStream_t stream) {
    const float* leaf  = (const float*)d_in[0];   // [8192,32]
    const float* iem   = (const float*)d_in[1];   // [8191,32]
    const float* trans = (const float*)d_in[2];   // [32,32,32]
    float* out = (float*)d_out;                   // [32]

    float* s1     = (float*)d_ws;                 // 256*32 f32   [0, 8192)
    float* s2     = s1 + 256 * 32;                // 16*32 f32    [8192, 8704)
    unsigned* cnt = (unsigned*)(s2 + 16 * 32);    // 1 u32 @ 8704, never reset
    float* wsE    = (float*)d_ws + 8720;          // 32768 f32, 16B-aligned

    (void)hipFuncSetAttribute((const void*)k1_kernel,
                              hipFuncAttributeMaxDynamicSharedMemorySize,
                              (int)SMEM_BYTES);
    (void)hipFuncSetAttribute((const void*)tail_kernel,
                              hipFuncAttributeMaxDynamicSharedMemorySize,
                              (int)SMEM_BYTES);

    k1_kernel<<<256, NT, SMEM_BYTES, stream>>>(leaf, s1, iem, trans, wsE);
    tail_kernel<<<16, NT, SMEM_BYTES, stream>>>(s1, s2, out, iem, wsE, cnt);
}